// Round 6
// baseline (257.542 us; speedup 1.0000x reference)
//
#include <hip/hip_runtime.h>
#include <hip/hip_bf16.h>

#define NPIX 4096
#define CCH  256
#define QSCALE 0.090168437f   // 1/(16*ln2): fold energy/16 and base-2 exp into Q

typedef __attribute__((ext_vector_type(8))) short short8;
typedef __attribute__((ext_vector_type(4))) short short4v;
typedef __attribute__((ext_vector_type(4))) float f32x4;
typedef __attribute__((ext_vector_type(16))) float f32x16;
typedef __attribute__((ext_vector_type(4))) int i32x4;

static __device__ __forceinline__ short f2bf(float f){
  __hip_bfloat16 h = __float2bfloat16(f);
  unsigned short u; __builtin_memcpy(&u, &h, 2); return (short)u;
}
static __device__ __forceinline__ float bf2f(short s){
  unsigned short u = (unsigned short)s;
  __hip_bfloat16 h; __builtin_memcpy(&h, &u, 2); return __bfloat162float(h);
}
static __device__ __forceinline__ short8 ld8(const short* p){
  return *(const short8*)p;
}
static __device__ __forceinline__ float fexp2(float x){
  float r; asm("v_exp_f32 %0, %1" : "=v"(r) : "v"(x)); return r;
}
static __device__ __forceinline__ void gl_lds16(const short* g, short* l){
  __builtin_amdgcn_global_load_lds(
    (const __attribute__((address_space(1))) unsigned int*)g,
    (__attribute__((address_space(3))) unsigned int*)l,
    16, 0, 0);
}

// ---- weights f32 -> bf16 (Wq pre-scaled by QSCALE) ----------------------
__global__ void k_cvtw(const float* __restrict__ Wq, const float* __restrict__ Wk,
                       const float* __restrict__ Wv, short* __restrict__ Wb){
  int i = blockIdx.x * 256 + threadIdx.x;          // 131072 total
  float v;
  if (i < 32768)        v = Wq[i] * QSCALE;
  else if (i < 65536)   v = Wk[i - 32768];
  else                  v = Wv[i - 65536];
  Wb[i] = f2bf(v);
}

// ---- x[b,c,n] f32 -> xt[b,n,c] bf16 (64x64 LDS tile transpose) ----------
__global__ __launch_bounds__(256) void k_transpose(const float* __restrict__ x,
                                                   short* __restrict__ xt){
  __shared__ short tile[64][66];
  int n0 = blockIdx.x * 64, c0 = blockIdx.y * 64, b = blockIdx.z;
  const float* xb = x + (size_t)b * CCH * NPIX;
  short* xtb = xt + (size_t)b * NPIX * CCH;
  int t = threadIdx.x;
  int nj = t & 63;
  for (int ci = t >> 6; ci < 64; ci += 4)
    tile[nj][ci] = f2bf(xb[(size_t)(c0 + ci) * NPIX + n0 + nj]);
  __syncthreads();
  int ci = t & 63;
  for (int nj2 = t >> 6; nj2 < 64; nj2 += 4)
    xtb[(size_t)(n0 + nj2) * CCH + c0 + ci] = tile[nj2][ci];
}

// ---- Q,K projections (MFMA). Q -> linear [b][n][128].
//      K -> swizzled tiles [b][tile=n>>5][row=n&31][chunk^(row&15)][8].
__global__ __launch_bounds__(256) void k_proj_qk(
    const short* __restrict__ xt, const short* __restrict__ Wb,
    const float* __restrict__ bq, const float* __restrict__ bk,
    short* __restrict__ Qt, short* __restrict__ Kt){
  int b = blockIdx.y, t = threadIdx.x;
  int w = t >> 6, l = t & 63, lrow = l & 15, lgrp = l >> 4;
  int n0 = blockIdx.x * 64 + w * 16;
  const short* xa = xt + ((size_t)b * NPIX + n0 + lrow) * CCH + lgrp * 8;
  short8 a[8];
  #pragma unroll
  for (int kk = 0; kk < 8; kk++) a[kk] = ld8(xa + kk * 32);
  #pragma unroll
  for (int which = 0; which < 2; which++){
    const short* W = Wb + (which ? 32768 : 0);
    const float* bias = which ? bk : bq;
    float bscale = which ? 1.0f : QSCALE;
    #pragma unroll
    for (int ot = 0; ot < 8; ot++){
      f32x4 acc = {0.f, 0.f, 0.f, 0.f};
      const short* wp = W + (size_t)(ot * 16 + lrow) * CCH + lgrp * 8;
      #pragma unroll
      for (int kk = 0; kk < 8; kk++)
        acc = __builtin_amdgcn_mfma_f32_16x16x32_bf16(a[kk], ld8(wp + kk * 32), acc, 0, 0, 0);
      int o = ot * 16 + lrow;                 // D col = lane&15
      float be = bias[o] * bscale;
      #pragma unroll
      for (int r = 0; r < 4; r++){            // D row = (lane>>4)*4 + r
        int n = n0 + lgrp * 4 + r;
        float v = acc[r] + be;
        if (which == 0){
          Qt[((size_t)b * NPIX + n) * 128 + o] = f2bf(v);
        } else {
          int row = n & 31;
          size_t off = (((size_t)b * 128 + (n >> 5)) * 32 + row) * 128
                     + (size_t)(((o >> 3) ^ (row & 15)) * 8) + (o & 7);
          Kt[off] = f2bf(v);
        }
      }
    }
  }
}

// ---- V projection -> swizzled tiles [b][tile=n>>5][ch][jchunk^(ch&3)][8] --
__global__ __launch_bounds__(256) void k_proj_v(
    const short* __restrict__ xt, const short* __restrict__ Wb,
    const float* __restrict__ bv, short* __restrict__ Vc){
  int b = blockIdx.y, t = threadIdx.x;
  int w = t >> 6, l = t & 63, lrow = l & 15, lgrp = l >> 4;
  int n0 = blockIdx.x * 64 + w * 16;
  const short* xb = xt + ((size_t)b * NPIX + n0 + lrow) * CCH + lgrp * 8;
  short8 xf[8];
  #pragma unroll
  for (int kk = 0; kk < 8; kk++) xf[kk] = ld8(xb + kk * 32);
  const short* Wv = Wb + 65536;
  int n = n0 + lrow;
  int tile = n >> 5, jr = n & 31;
  size_t tbase = ((size_t)b * 128 + tile) * 8192;
  #pragma unroll
  for (int ot = 0; ot < 16; ot++){
    f32x4 acc = {0.f, 0.f, 0.f, 0.f};
    const short* wp = Wv + (size_t)(ot * 16 + lrow) * CCH + lgrp * 8;
    #pragma unroll
    for (int kk = 0; kk < 8; kk++)
      acc = __builtin_amdgcn_mfma_f32_16x16x32_bf16(ld8(wp + kk * 32), xf[kk], acc, 0, 0, 0);
    #pragma unroll
    for (int r = 0; r < 4; r++){
      int o = ot * 16 + lgrp * 4 + r;         // channel
      size_t off = tbase + (size_t)o * 32 + (size_t)(((jr >> 3) ^ (o & 3)) * 8) + (jr & 7);
      Vc[off] = f2bf(acc[r] + bv[o]);
    }
  }
}

// ---- flash attention: 32x32x16, swapped QK^T, P in registers.
//      512 blocks x 256 thr: 4 waves = 2 q-groups x 2 ch-halves, all sweep
//      128 KV tiles. Each wave reads K(8KB) + its V ch-half(8KB) per iter
//      -> 64 FLOP/LDS-byte. 2 blocks/CU (LDS 48.3KB), 8 waves/CU.
__global__ __launch_bounds__(256, 2) void k_attn(
    const short* __restrict__ Qt, const short* __restrict__ Kt,
    const short* __restrict__ Vc, const float* __restrict__ x,
    const float* __restrict__ gamma, float* __restrict__ out){
  extern __shared__ __align__(16) short smem[];   // 2 x 12288 shorts + lsum
  float* lsumLds = (float*)(smem + 24576);        // 64 f32
  int bid = blockIdx.x;
  int b = bid & 7;                                 // batch == XCD
  int n0 = (bid >> 3) * 64;                        // 64 q-rows per block
  int t = threadIdx.x;                             // 0..255
  int w = t >> 6;                                  // wave 0..3
  int qg = w & 1;                                  // q-group (32 rows)
  int chh = w >> 1;                                // channel half 0/1
  int l = t & 63;
  int lq = l & 31;
  int h = l >> 5;
  int q0w = n0 + qg * 32;

  const short* ktb = Kt + (size_t)b * (128 * 4096);
  const short* vtb = Vc + (size_t)b * (128 * 8192);

  // Q B-frags (col q = lq, k = kt*16 + h*8 + e), persistent in regs
  short8 qf[8];
  const short* qp = Qt + ((size_t)b * NPIX + q0w + lq) * 128 + h * 8;
  #pragma unroll
  for (int kt = 0; kt < 8; kt++) qf[kt] = ld8(qp + kt * 16);
  asm volatile("s_waitcnt vmcnt(0)" ::: "memory");
  #pragma unroll
  for (int kt = 0; kt < 8; kt++) asm volatile("" : "+v"(qf[kt]));

  // prologue: stage tile 0
  {
    short* dK = smem; short* dV = smem + 4096;
    #pragma unroll
    for (int i = 0; i < 2; i++) gl_lds16(ktb + (i * 256 + t) * 8, dK + (i * 256 + t) * 8);
    #pragma unroll
    for (int i = 0; i < 4; i++) gl_lds16(vtb + (i * 256 + t) * 8, dV + (i * 256 + t) * 8);
  }

  f32x16 accO[4];
  #pragma unroll
  for (int ct = 0; ct < 4; ct++) accO[ct] = (f32x16)0.0f;
  float lsum = 0.0f;

  for (int it = 0; it < 128; it++){
    int cur = it & 1;
    if (it < 127){
      const short* gK = ktb + (size_t)(it + 1) * 4096;
      const short* gV = vtb + (size_t)(it + 1) * 8192;
      short* dK = smem + (cur ^ 1) * 12288;
      short* dV = dK + 4096;
      #pragma unroll
      for (int i = 0; i < 2; i++) gl_lds16(gK + (i * 256 + t) * 8, dK + (i * 256 + t) * 8);
      #pragma unroll
      for (int i = 0; i < 4; i++) gl_lds16(gV + (i * 256 + t) * 8, dV + (i * 256 + t) * 8);
      asm volatile("s_waitcnt vmcnt(6)" ::: "memory");
    } else {
      asm volatile("s_waitcnt vmcnt(0)" ::: "memory");
    }
    __builtin_amdgcn_sched_barrier(0);
    __builtin_amdgcn_s_barrier();
    __builtin_amdgcn_sched_barrier(0);

    const short* Ks = smem + cur * 12288;
    const short* Vs = Ks + 4096;

    // --- St = K . Q^T : C col = q = lq (lane-local); 2 parity chains ---
    f32x16 a0 = (f32x16)0.0f, a1 = (f32x16)0.0f;
    #pragma unroll
    for (int kt = 0; kt < 8; kt += 2){
      short8 k0 = ld8(Ks + lq * 128 + ((((kt + 0) * 2 + h) ^ (lq & 15)) * 8));
      short8 k1 = ld8(Ks + lq * 128 + ((((kt + 1) * 2 + h) ^ (lq & 15)) * 8));
      a0 = __builtin_amdgcn_mfma_f32_32x32x16_bf16(k0, qf[kt + 0], a0, 0, 0, 0);
      a1 = __builtin_amdgcn_mfma_f32_32x32x16_bf16(k1, qf[kt + 1], a1, 0, 0, 0);
    }

    // --- P = exp2(St) (|s2| small: no max subtraction), lane-local sum ---
    float p[16]; float rs = 0.0f;
    #pragma unroll
    for (int r = 0; r < 16; r++) p[r] = fexp2(a0[r] + a1[r]);
    #pragma unroll
    for (int r = 0; r < 16; r++) rs += p[r];
    lsum += rs;

    // --- pack P -> A-frags in-register (cvt_pk + permlane32_swap) ---
    short8 pa[2];
    #pragma unroll
    for (int jt = 0; jt < 2; jt++){
      int base = jt * 8;
      unsigned A, B, C, D;
      asm("v_cvt_pk_bf16_f32 %0, %1, %2" : "=v"(A) : "v"(p[base + 0]), "v"(p[base + 1]));
      asm("v_cvt_pk_bf16_f32 %0, %1, %2" : "=v"(B) : "v"(p[base + 2]), "v"(p[base + 3]));
      asm("v_cvt_pk_bf16_f32 %0, %1, %2" : "=v"(C) : "v"(p[base + 4]), "v"(p[base + 5]));
      asm("v_cvt_pk_bf16_f32 %0, %1, %2" : "=v"(D) : "v"(p[base + 6]), "v"(p[base + 7]));
      asm("v_permlane32_swap_b32 %0, %1" : "+v"(A), "+v"(C));
      asm("v_permlane32_swap_b32 %0, %1" : "+v"(B), "+v"(D));
      union { i32x4 i; short8 v; } u;
      u.i = (i32x4){(int)A, (int)B, (int)C, (int)D};
      pa[jt] = u.v;
    }

    // --- O += P . V  over this wave's channel half ---
    #pragma unroll
    for (int ct = 0; ct < 4; ct++){
      int ch = chh * 128 + ct * 32 + lq;
      short8 v0 = ld8(Vs + ch * 32 + (((0 + h) ^ (lq & 3)) * 8));
      short8 v1 = ld8(Vs + ch * 32 + (((2 + h) ^ (lq & 3)) * 8));
      accO[ct] = __builtin_amdgcn_mfma_f32_32x32x16_bf16(pa[0], v0, accO[ct], 0, 0, 0);
      accO[ct] = __builtin_amdgcn_mfma_f32_32x32x16_bf16(pa[1], v1, accO[ct], 0, 0, 0);
    }

    __builtin_amdgcn_sched_barrier(0);
    __builtin_amdgcn_s_barrier();   // protect buf[cur^1] before next stage
  }

  // --- lsum: merge lane halves; chh==0 publishes (both halves identical) ---
  float lt = lsum + __shfl_xor(lsum, 32);
  if (chh == 0) lsumLds[qg * 32 + lq] = lt;
  __syncthreads();

  // --- normalize + stage O bf16 to LDS (reuse buf region) ---
  short (*Olds)[258] = (short (*)[258])smem;   // 64 x 258 shorts = 33 KB
  float rlv[16];
  #pragma unroll
  for (int r = 0; r < 16; r++){
    int qrow = (r & 3) + 8 * (r >> 2) + 4 * h;
    rlv[r] = 1.0f / lsumLds[qg * 32 + qrow];
  }
  #pragma unroll
  for (int ct = 0; ct < 4; ct++){
    #pragma unroll
    for (int r = 0; r < 16; r++){
      int qrow = (r & 3) + 8 * (r >> 2) + 4 * h;
      Olds[qg * 32 + qrow][chh * 128 + ct * 32 + lq] = f2bf(accO[ct][r] * rlv[r]);
    }
  }
  __syncthreads();

  // --- coalesced epilogue: out[b,c,n0+j] = gamma*O + x ---
  float g = gamma[0];
  int j = t & 63, cseg = t >> 6;
  const float* xb = x + (size_t)b * CCH * NPIX + n0 + j;
  float* ob = out + (size_t)b * CCH * NPIX + n0 + j;
  #pragma unroll 4
  for (int cc = 0; cc < 64; cc++){
    int c = cseg * 64 + cc;
    size_t idx = (size_t)c * NPIX;
    ob[idx] = g * bf2f(Olds[j][c]) + xb[idx];
  }
}

extern "C" void kernel_launch(void* const* d_in, const int* in_sizes, int n_in,
                              void* d_out, int out_size, void* d_ws, size_t ws_size,
                              hipStream_t stream){
  const float* x     = (const float*)d_in[0];
  const float* Wq    = (const float*)d_in[1];
  const float* bq    = (const float*)d_in[2];
  const float* Wk    = (const float*)d_in[3];
  const float* bk    = (const float*)d_in[4];
  const float* Wv    = (const float*)d_in[5];
  const float* bv    = (const float*)d_in[6];
  const float* gamma = (const float*)d_in[7];
  float* out = (float*)d_out;

  char* ws = (char*)d_ws;
  short* xt = (short*)ws;                    // 16,777,216 B
  short* Qt = (short*)(ws + 16777216);       //  8,388,608 B
  short* Kt = (short*)(ws + 25165824);       //  8,388,608 B (swizzled tiles)
  short* Vc = (short*)(ws + 33554432);       // 16,777,216 B (swizzled tiles)
  short* Wb = (short*)(ws + 50331648);       //    262,144 B

  hipLaunchKernelGGL(k_cvtw,      dim3(512),      dim3(256), 0, stream, Wq, Wk, Wv, Wb);
  hipLaunchKernelGGL(k_transpose, dim3(64, 4, 8), dim3(256), 0, stream, x, xt);
  hipLaunchKernelGGL(k_proj_qk,   dim3(64, 8),    dim3(256), 0, stream, xt, Wb, bq, bk, Qt, Kt);
  hipLaunchKernelGGL(k_proj_v,    dim3(64, 8),    dim3(256), 0, stream, xt, Wb, bv, Vc);
  hipLaunchKernelGGL(k_attn,      dim3(512),      dim3(256), 49408, stream, Qt, Kt, Vc, x, gamma, out);
}

// Round 7
// 204.637 us; speedup vs baseline: 1.2585x; 1.2585x over previous
//
#include <hip/hip_runtime.h>
#include <hip/hip_bf16.h>

#define NPIX 4096
#define CCH  256
#define QSCALE 0.090168437f   // 1/(16*ln2): fold energy/16 and base-2 exp into Q

typedef __attribute__((ext_vector_type(8))) short short8;
typedef __attribute__((ext_vector_type(4))) short short4v;
typedef __attribute__((ext_vector_type(4))) float f32x4;
typedef __attribute__((ext_vector_type(16))) float f32x16;
typedef __attribute__((ext_vector_type(4))) int i32x4;

static __device__ __forceinline__ short f2bf(float f){
  __hip_bfloat16 h = __float2bfloat16(f);
  unsigned short u; __builtin_memcpy(&u, &h, 2); return (short)u;
}
static __device__ __forceinline__ float bf2f(short s){
  unsigned short u = (unsigned short)s;
  __hip_bfloat16 h; __builtin_memcpy(&h, &u, 2); return __bfloat162float(h);
}
static __device__ __forceinline__ short8 ld8(const short* p){
  return *(const short8*)p;
}
static __device__ __forceinline__ float fexp2(float x){
  float r; asm("v_exp_f32 %0, %1" : "=v"(r) : "v"(x)); return r;
}
static __device__ __forceinline__ void gl_lds16(const short* g, short* l){
  __builtin_amdgcn_global_load_lds(
    (const __attribute__((address_space(1))) unsigned int*)g,
    (__attribute__((address_space(3))) unsigned int*)l,
    16, 0, 0);
}

// ---- weights f32 -> bf16 (Wq pre-scaled by QSCALE) ----------------------
__global__ void k_cvtw(const float* __restrict__ Wq, const float* __restrict__ Wk,
                       const float* __restrict__ Wv, short* __restrict__ Wb){
  int i = blockIdx.x * 256 + threadIdx.x;          // 131072 total
  float v;
  if (i < 32768)        v = Wq[i] * QSCALE;
  else if (i < 65536)   v = Wk[i - 32768];
  else                  v = Wv[i - 65536];
  Wb[i] = f2bf(v);
}

// ---- x[b,c,n] f32 -> xt[b,n,c] bf16 (64x64 LDS tile transpose) ----------
__global__ __launch_bounds__(256) void k_transpose(const float* __restrict__ x,
                                                   short* __restrict__ xt){
  __shared__ short tile[64][66];
  int n0 = blockIdx.x * 64, c0 = blockIdx.y * 64, b = blockIdx.z;
  const float* xb = x + (size_t)b * CCH * NPIX;
  short* xtb = xt + (size_t)b * NPIX * CCH;
  int t = threadIdx.x;
  int nj = t & 63;
  for (int ci = t >> 6; ci < 64; ci += 4)
    tile[nj][ci] = f2bf(xb[(size_t)(c0 + ci) * NPIX + n0 + nj]);
  __syncthreads();
  int ci = t & 63;
  for (int nj2 = t >> 6; nj2 < 64; nj2 += 4)
    xtb[(size_t)(n0 + nj2) * CCH + c0 + ci] = tile[nj2][ci];
}

// ---- Q,K projections (MFMA). Q -> linear [b][n][128].
//      K -> tiles [b][tile=n>>5]; 16B-chunk (row=n&31, kc=o>>3) at physical
//      chunk (kc>>1)*64 + (kc&1)*32 + row  => consumer reads are LINEAR.
__global__ __launch_bounds__(256) void k_proj_qk(
    const short* __restrict__ xt, const short* __restrict__ Wb,
    const float* __restrict__ bq, const float* __restrict__ bk,
    short* __restrict__ Qt, short* __restrict__ Kt){
  int b = blockIdx.y, t = threadIdx.x;
  int w = t >> 6, l = t & 63, lrow = l & 15, lgrp = l >> 4;
  int n0 = blockIdx.x * 64 + w * 16;
  const short* xa = xt + ((size_t)b * NPIX + n0 + lrow) * CCH + lgrp * 8;
  short8 a[8];
  #pragma unroll
  for (int kk = 0; kk < 8; kk++) a[kk] = ld8(xa + kk * 32);
  #pragma unroll
  for (int which = 0; which < 2; which++){
    const short* W = Wb + (which ? 32768 : 0);
    const float* bias = which ? bk : bq;
    float bscale = which ? 1.0f : QSCALE;
    #pragma unroll
    for (int ot = 0; ot < 8; ot++){
      f32x4 acc = {0.f, 0.f, 0.f, 0.f};
      const short* wp = W + (size_t)(ot * 16 + lrow) * CCH + lgrp * 8;
      #pragma unroll
      for (int kk = 0; kk < 8; kk++)
        acc = __builtin_amdgcn_mfma_f32_16x16x32_bf16(a[kk], ld8(wp + kk * 32), acc, 0, 0, 0);
      int o = ot * 16 + lrow;                 // D col = lane&15
      float be = bias[o] * bscale;
      #pragma unroll
      for (int r = 0; r < 4; r++){            // D row = (lane>>4)*4 + r
        int n = n0 + lgrp * 4 + r;
        float v = acc[r] + be;
        if (which == 0){
          Qt[((size_t)b * NPIX + n) * 128 + o] = f2bf(v);
        } else {
          int row = n & 31;
          int chunk = (o >> 4) * 64 + ((o >> 3) & 1) * 32 + row;
          size_t off = (((size_t)b * 128 + (n >> 5)) * 512 + chunk) * 8 + (o & 7);
          Kt[off] = f2bf(v);
        }
      }
    }
  }
}

// ---- V projection -> tiles [b][tile=n>>5]; chunk (ch=o, jc=(n&31)>>3) at
//      physical (ch>>5)*128 + (jc>>1)*64 + (jc&1)*32 + (ch&31). ------------
__global__ __launch_bounds__(256) void k_proj_v(
    const short* __restrict__ xt, const short* __restrict__ Wb,
    const float* __restrict__ bv, short* __restrict__ Vc){
  int b = blockIdx.y, t = threadIdx.x;
  int w = t >> 6, l = t & 63, lrow = l & 15, lgrp = l >> 4;
  int n0 = blockIdx.x * 64 + w * 16;
  const short* xb = xt + ((size_t)b * NPIX + n0 + lrow) * CCH + lgrp * 8;
  short8 xf[8];
  #pragma unroll
  for (int kk = 0; kk < 8; kk++) xf[kk] = ld8(xb + kk * 32);
  const short* Wv = Wb + 65536;
  int n = n0 + lrow;
  int tile = n >> 5, jr = n & 31;
  int jc = jr >> 3;
  size_t tbase = ((size_t)b * 128 + tile) * 8192;
  #pragma unroll
  for (int ot = 0; ot < 16; ot++){
    f32x4 acc = {0.f, 0.f, 0.f, 0.f};
    const short* wp = Wv + (size_t)(ot * 16 + lrow) * CCH + lgrp * 8;
    #pragma unroll
    for (int kk = 0; kk < 8; kk++)
      acc = __builtin_amdgcn_mfma_f32_16x16x32_bf16(ld8(wp + kk * 32), xf[kk], acc, 0, 0, 0);
    #pragma unroll
    for (int r = 0; r < 4; r++){
      int o = ot * 16 + lgrp * 4 + r;         // channel
      int chunk = (o >> 5) * 128 + (jc >> 1) * 64 + (jc & 1) * 32 + (o & 31);
      Vc[tbase + (size_t)chunk * 8 + (jr & 7)] = f2bf(acc[r] + bv[o]);
    }
  }
}

// ---- flash attention: 32x32x16, swapped QK^T, P in registers.
//      256 blocks x 512 thr: 8 waves = 4 q-groups x 2 KV-halves.
//      Triple-buffered staging, ONE barrier/iter, linear LDS reads.
__global__ __launch_bounds__(512, 1) void k_attn(
    const short* __restrict__ Qt, const short* __restrict__ Kt,
    const short* __restrict__ Vc, const float* __restrict__ x,
    const float* __restrict__ gamma, float* __restrict__ out){
  extern __shared__ __align__(16) short smem[];
  // layout: 6 buffers (s*3+bi)*12288 shorts (24KB each: K 4096 | V 8192)
  //         lsumLds = (float*)(smem + 73728)   (2 x 128 f32)
  float* lsumLds = (float*)(smem + 73728);
  int bid = blockIdx.x;
  int b = bid & 7;                                 // batch == XCD
  int n0 = (bid >> 3) * 128;                       // 128 q-rows per block
  int t = threadIdx.x;                             // 0..511
  int w = t >> 6;                                  // wave 0..7
  int qg = w & 3;                                  // q-group (32 rows each)
  int s = w >> 2;                                  // KV half 0/1
  int l = t & 63;
  int lq = l & 31;
  int h = l >> 5;
  int ts = t & 255;                                // staging lane within half
  int q0w = n0 + qg * 32;

  const short* ktb = Kt + (size_t)b * (128 * 4096);
  const short* vtb = Vc + (size_t)b * (128 * 8192);

  // Q B-frags (col q = lq, k = kt*16 + h*8 + e), persistent in regs
  short8 qf[8];
  const short* qp = Qt + ((size_t)b * NPIX + q0w + lq) * 128 + h * 8;
  #pragma unroll
  for (int kt = 0; kt < 8; kt++) qf[kt] = ld8(qp + kt * 16);
  asm volatile("s_waitcnt vmcnt(0)" ::: "memory");
  #pragma unroll
  for (int kt = 0; kt < 8; kt++) asm volatile("" : "+v"(qf[kt]));

  // prologue: stage this half's tile 0 into buffer (s,0)
  {
    short* dK = smem + (s * 3 + 0) * 12288;
    short* dV = dK + 4096;
    const short* gK = ktb + (size_t)(s * 64) * 4096;
    const short* gV = vtb + (size_t)(s * 64) * 8192;
    #pragma unroll
    for (int i = 0; i < 2; i++) gl_lds16(gK + (i * 256 + ts) * 8, dK + (i * 256 + ts) * 8);
    #pragma unroll
    for (int i = 0; i < 4; i++) gl_lds16(gV + (i * 256 + ts) * 8, dV + (i * 256 + ts) * 8);
  }

  f32x16 accO[8];
  #pragma unroll
  for (int ct = 0; ct < 8; ct++) accO[ct] = (f32x16)0.0f;
  float lsum = 0.0f;

  int bi = 0;                  // current buffer index (it % 3)
  for (int it = 0; it < 64; it++){
    int bn = (bi == 2) ? 0 : bi + 1;
    if (it < 63){
      const short* gK = ktb + (size_t)(s * 64 + it + 1) * 4096;
      const short* gV = vtb + (size_t)(s * 64 + it + 1) * 8192;
      short* dK = smem + (s * 3 + bn) * 12288;
      short* dV = dK + 4096;
      #pragma unroll
      for (int i = 0; i < 2; i++) gl_lds16(gK + (i * 256 + ts) * 8, dK + (i * 256 + ts) * 8);
      #pragma unroll
      for (int i = 0; i < 4; i++) gl_lds16(gV + (i * 256 + ts) * 8, dV + (i * 256 + ts) * 8);
      asm volatile("s_waitcnt vmcnt(6)" ::: "memory");
    } else {
      asm volatile("s_waitcnt vmcnt(0)" ::: "memory");
    }
    __builtin_amdgcn_s_barrier();
    __builtin_amdgcn_sched_barrier(0);

    const short* Ks = smem + (s * 3 + bi) * 12288;
    const short* Vs = Ks + 4096;

    // --- St = K . Q^T : linear LDS reads (base + lane*16B) ---
    f32x16 a0 = (f32x16)0.0f, a1 = (f32x16)0.0f;
    __builtin_amdgcn_s_setprio(1);
    #pragma unroll
    for (int j = 0; j < 8; j += 2){
      short8 k0 = ld8(Ks + (j + 0) * 512 + l * 8);
      short8 k1 = ld8(Ks + (j + 1) * 512 + l * 8);
      a0 = __builtin_amdgcn_mfma_f32_32x32x16_bf16(k0, qf[j + 0], a0, 0, 0, 0);
      a1 = __builtin_amdgcn_mfma_f32_32x32x16_bf16(k1, qf[j + 1], a1, 0, 0, 0);
    }
    __builtin_amdgcn_s_setprio(0);

    // --- P = exp2(St) (|s2| small: no max subtraction), lane-local sum ---
    float p[16]; float rs = 0.0f;
    #pragma unroll
    for (int r = 0; r < 16; r++) p[r] = fexp2(a0[r] + a1[r]);
    #pragma unroll
    for (int r = 0; r < 16; r++) rs += p[r];
    lsum += rs;

    // --- pack P -> A-frags in-register (cvt_pk + permlane32_swap) ---
    short8 pa[2];
    #pragma unroll
    for (int jt = 0; jt < 2; jt++){
      int base = jt * 8;
      unsigned A, B, C, D;
      asm("v_cvt_pk_bf16_f32 %0, %1, %2" : "=v"(A) : "v"(p[base + 0]), "v"(p[base + 1]));
      asm("v_cvt_pk_bf16_f32 %0, %1, %2" : "=v"(B) : "v"(p[base + 2]), "v"(p[base + 3]));
      asm("v_cvt_pk_bf16_f32 %0, %1, %2" : "=v"(C) : "v"(p[base + 4]), "v"(p[base + 5]));
      asm("v_cvt_pk_bf16_f32 %0, %1, %2" : "=v"(D) : "v"(p[base + 6]), "v"(p[base + 7]));
      asm("v_permlane32_swap_b32 %0, %1" : "+v"(A), "+v"(C));
      asm("v_permlane32_swap_b32 %0, %1" : "+v"(B), "+v"(D));
      union { i32x4 i; short8 v; } u;
      u.i = (i32x4){(int)A, (int)B, (int)C, (int)D};
      pa[jt] = u.v;
    }

    // --- O += P . V : linear LDS reads ---
    __builtin_amdgcn_s_setprio(1);
    #pragma unroll
    for (int ct = 0; ct < 8; ct++){
      short8 v0 = ld8(Vs + ct * 1024 + l * 8);
      short8 v1 = ld8(Vs + ct * 1024 + 512 + l * 8);
      accO[ct] = __builtin_amdgcn_mfma_f32_32x32x16_bf16(pa[0], v0, accO[ct], 0, 0, 0);
      accO[ct] = __builtin_amdgcn_mfma_f32_32x32x16_bf16(pa[1], v1, accO[ct], 0, 0, 0);
    }
    __builtin_amdgcn_s_setprio(0);

    bi = bn;
  }

  // --- lsum: merge lane halves, publish per KV-half ---
  float lt = lsum + __shfl_xor(lsum, 32);
  lsumLds[s * 128 + qg * 32 + lq] = lt;
  __syncthreads();

  // --- merge O across KV halves (pure add: no max tracking) ---
  float* Mf = (float*)smem;                 // 4*32*128 f32 = 64KB scratch
  #pragma unroll
  for (int round = 0; round < 2; round++){
    if (s == 1){
      #pragma unroll
      for (int cti = 0; cti < 4; cti++){
        int ct = round * 4 + cti;
        #pragma unroll
        for (int r = 0; r < 16; r++){
          int qrow = (r & 3) + 8 * (r >> 2) + 4 * h;
          Mf[((qg * 32 + qrow) << 7) + cti * 32 + lq] = accO[ct][r];
        }
      }
    }
    __syncthreads();
    if (s == 0){
      #pragma unroll
      for (int cti = 0; cti < 4; cti++){
        int ct = round * 4 + cti;
        #pragma unroll
        for (int r = 0; r < 16; r++){
          int qrow = (r & 3) + 8 * (r >> 2) + 4 * h;
          accO[ct][r] += Mf[((qg * 32 + qrow) << 7) + cti * 32 + lq];
        }
      }
    }
    __syncthreads();
  }

  // --- s==0 waves: normalize + stage O bf16 to LDS ---
  short (*Olds)[258] = (short (*)[258])smem;   // 128 x 258 shorts = 66KB
  if (s == 0){
    float rlv[16];
    #pragma unroll
    for (int r = 0; r < 16; r++){
      int qrow = (r & 3) + 8 * (r >> 2) + 4 * h;
      int qi = qg * 32 + qrow;
      rlv[r] = 1.0f / (lsumLds[qi] + lsumLds[128 + qi]);
    }
    #pragma unroll
    for (int ct = 0; ct < 8; ct++){
      #pragma unroll
      for (int r = 0; r < 16; r++){
        int qrow = (r & 3) + 8 * (r >> 2) + 4 * h;
        Olds[qg * 32 + qrow][ct * 32 + lq] = f2bf(accO[ct][r] * rlv[r]);
      }
    }
  }
  __syncthreads();

  // --- coalesced epilogue (all 512 threads): out = gamma*O + x ---
  float g = gamma[0];
  int j = t & 127, cg2 = t >> 7;
  const float* xb = x + (size_t)b * CCH * NPIX + n0 + j;
  float* ob = out + (size_t)b * CCH * NPIX + n0 + j;
  #pragma unroll 4
  for (int cc = 0; cc < 64; cc++){
    int c = cg2 * 64 + cc;
    size_t idx = (size_t)c * NPIX;
    ob[idx] = g * bf2f(Olds[j][c]) + xb[idx];
  }
}

extern "C" void kernel_launch(void* const* d_in, const int* in_sizes, int n_in,
                              void* d_out, int out_size, void* d_ws, size_t ws_size,
                              hipStream_t stream){
  const float* x     = (const float*)d_in[0];
  const float* Wq    = (const float*)d_in[1];
  const float* bq    = (const float*)d_in[2];
  const float* Wk    = (const float*)d_in[3];
  const float* bk    = (const float*)d_in[4];
  const float* Wv    = (const float*)d_in[5];
  const float* bv    = (const float*)d_in[6];
  const float* gamma = (const float*)d_in[7];
  float* out = (float*)d_out;

  char* ws = (char*)d_ws;
  short* xt = (short*)ws;                    // 16,777,216 B
  short* Qt = (short*)(ws + 16777216);       //  8,388,608 B
  short* Kt = (short*)(ws + 25165824);       //  8,388,608 B (permuted tiles)
  short* Vc = (short*)(ws + 33554432);       // 16,777,216 B (permuted tiles)
  short* Wb = (short*)(ws + 50331648);       //    262,144 B

  hipLaunchKernelGGL(k_cvtw,      dim3(512),      dim3(256), 0, stream, Wq, Wk, Wv, Wb);
  hipLaunchKernelGGL(k_transpose, dim3(64, 4, 8), dim3(256), 0, stream, x, xt);
  hipLaunchKernelGGL(k_proj_qk,   dim3(64, 8),    dim3(256), 0, stream, xt, Wb, bq, bk, Qt, Kt);
  hipLaunchKernelGGL(k_proj_v,    dim3(64, 8),    dim3(256), 0, stream, xt, Wb, bv, Vc);
  hipLaunchKernelGGL(k_attn,      dim3(256),      dim3(512), 148480, stream, Qt, Kt, Vc, x, gamma, out);
}